// Round 9
// baseline (10130.598 us; speedup 1.0000x reference)
//
#include <hip/hip_runtime.h>

typedef unsigned short u16;
typedef __bf16 bf16x8 __attribute__((ext_vector_type(8)));
typedef float f32x4 __attribute__((ext_vector_type(4)));

#define N_NODES 100000
#define D 256
#define NLAYER 4
#define E2N 300000
#define E3N 200000
#define TGT 2000

__device__ __forceinline__ u16 f2b(float f) {
    union { float f; unsigned u; } v; v.f = f;
    unsigned r = v.u + 0x7FFFu + ((v.u >> 16) & 1u);
    return (u16)(r >> 16);
}
__device__ __forceinline__ float b2f(u16 u) {
    union { unsigned u; float f; } v; v.u = ((unsigned)u) << 16; return v.f;
}

// ---------------- embedding gather ----------------
__global__ __launch_bounds__(256)
void embed_kernel(const int* __restrict__ x, const float* __restrict__ emb,
                  u16* __restrict__ hb, int n) {
    int wid = threadIdx.x >> 6, lane = threadIdx.x & 63;
    int row = blockIdx.x * 4 + wid;
    if (row >= n) return;
    int v = x[row];
    float4 f = *(const float4*)(emb + v * D + lane * 4);
    ushort4 o; o.x = f2b(f.x); o.y = f2b(f.y); o.z = f2b(f.z); o.w = f2b(f.w);
    *(ushort4*)(hb + row * D + lane * 4) = o;
}

// ---------------- W_root (L,K,N) f32 -> Wr (L,N,K) bf16 ----------------
__global__ __launch_bounds__(256)
void convert_wt(const float* __restrict__ W, u16* __restrict__ Wt,
                int total, int K, int N) {
    int idx = blockIdx.x * 256 + threadIdx.x;
    if (idx >= total) return;
    int kk = idx % K;
    int rem = idx / K;
    int nn = rem % N;
    int l  = rem / N;
    Wt[idx] = f2b(W[(l * K + kk) * N + nn]);
}

// ---------------- W_eA (L, A*256, A*256) -> Wcat[((l*A+s)*A+t)][c][k] ----------------
__global__ __launch_bounds__(256)
void convert_cat(const float* __restrict__ W, u16* __restrict__ Wt,
                 int A, int total) {
    int idx = blockIdx.x * 256 + threadIdx.x;
    if (idx >= total) return;
    int k = idx & 255;
    int c = (idx >> 8) & 255;
    int r = idx >> 16;           // (l*A + s)*A + t
    int t = r % A; int ls = r / A; int s = ls % A; int l = ls / A;
    int AD = A * 256;
    Wt[idx] = f2b(W[(size_t)(l * AD + t * 256 + k) * AD + s * 256 + c]);
}

// ---------------- counting sort: CSR (rowptr + edge-id col array) per (type,slot) ------
#define NBINS 100000
#define NSEG 5
#define TOTENT 1200000
#define RPW (NBINS + 1)

__global__ __launch_bounds__(256)
void zero_counts(int* __restrict__ counts) {
    int i = blockIdx.x * 256 + threadIdx.x;
    if (i < NSEG * NBINS) counts[i] = 0;
}

__device__ __forceinline__ void decode_entry(int i, const int* e2, const int* e3,
                                             int& seg, int& key, int& e, int& is2) {
    if (i < 2 * E2N) {
        int s = i / E2N; e = i - s * E2N;
        seg = s; key = e2[s * E2N + e]; is2 = 1;
    } else {
        int j = i - 2 * E2N; int s = j / E3N; e = j - s * E3N;
        seg = 2 + s; key = e3[s * E3N + e]; is2 = 0;
    }
}

__global__ __launch_bounds__(256)
void hist_kernel(const int* __restrict__ e2, const int* __restrict__ e3,
                 int* __restrict__ counts) {
    int i = blockIdx.x * 256 + threadIdx.x;
    if (i >= TOTENT) return;
    int seg, key, e, is2;
    decode_entry(i, e2, e3, seg, key, e, is2);
    atomicAdd(counts + seg * NBINS + key, 1);
}

__global__ __launch_bounds__(1024)
void scan_kernel(int* __restrict__ counts) {
    __shared__ int ps[1024];
    int* seg = counts + blockIdx.x * NBINS;
    int t = threadIdx.x;
    const int C = (NBINS + 1023) / 1024;
    int b = t * C, en = b + C; if (en > NBINS) en = NBINS; if (b > NBINS) b = NBINS;
    int s = 0;
    for (int i = b; i < en; ++i) s += seg[i];
    ps[t] = s; __syncthreads();
    for (int off = 1; off < 1024; off <<= 1) {
        int v = ps[t];
        if (t >= off) v += ps[t - off];
        __syncthreads();
        ps[t] = v; __syncthreads();
    }
    int run = (t == 0) ? 0 : ps[t - 1];
    for (int i = b; i < en; ++i) { int c = seg[i]; seg[i] = run; run += c; }
}

// preserve rowptr before scatter destroys the cursors
__global__ __launch_bounds__(256)
void copy_rowptr(const int* __restrict__ counts, int* __restrict__ rp) {
    int i = blockIdx.x * 256 + threadIdx.x;
    if (i >= NSEG * RPW) return;
    int seg = i / RPW, k = i - seg * RPW;
    rp[i] = (k < NBINS) ? counts[seg * NBINS + k] : (seg < 2 ? E2N : E3N);
}

__global__ __launch_bounds__(256)
void scatter_kernel(const int* __restrict__ e2, const int* __restrict__ e3,
                    int* __restrict__ counts, int* __restrict__ sorted2,
                    int* __restrict__ sorted3) {
    int i = blockIdx.x * 256 + threadIdx.x;
    if (i >= TOTENT) return;
    int seg, key, e, is2;
    decode_entry(i, e2, e3, seg, key, e, is2);
    int pos = atomicAdd(counts + seg * NBINS + key, 1);
    if (is2) sorted2[seg * E2N + pos] = e;
    else     sorted3[(seg - 2) * E3N + pos] = e;
}

// ---------------- CSR gather-aggregate: G_t[n-n0,:] = sum_{e: dst=n} h[src_t(e),:] ------
// Each dst node owned by exactly one block: no atomics, no memset, coalesced G writes.
template<int ARITY>
__global__ __launch_bounds__(256)
void gather_agg(const u16* __restrict__ hb, const int* __restrict__ eidx,
                const int* __restrict__ csr, const int* __restrict__ rp,
                u16* __restrict__ G, int n0, int nrows, int E, int mstride) {
    const int c = threadIdx.x;
    const int base = blockIdx.x * 8;
#pragma unroll 1
    for (int i = 0; i < 8; ++i) {
        int loc = base + i;
        if (loc >= nrows) return;
        int n = n0 + loc;
        int e0 = rp[n], e1 = rp[n + 1];
        float acc[ARITY];
#pragma unroll
        for (int t = 0; t < ARITY; ++t) acc[t] = 0.f;
        for (int e = e0; e < e1; ++e) {
            int entry = csr[e];
#pragma unroll
            for (int t = 0; t < ARITY; ++t)
                acc[t] += b2f(hb[(size_t)eidx[t * E + entry] * 256 + c]);
        }
#pragma unroll
        for (int t = 0; t < ARITY; ++t)
            G[(size_t)t * mstride + (size_t)loc * 256 + c] = f2b(acc[t]);
    }
}

// ---------------- GEMM: agg[m,:] (+)= sum_slots A_slot[m,:] @ B_slot ----------------
// A: NSLOT blocks of [M x 256] bf16 (stride ablk elems). B: NSLOT blocks of 256x256
// (row-major N x K, stride 65536). INIT: '=' (root). Else '+=' (rows block-exclusive).
#define LDSP 144
#define BOFF 9216          // 64*144

template<int NSLOT, bool INIT>
__global__ __launch_bounds__(256)
void gemm_acc(const u16* __restrict__ A0, size_t ablk,
              const u16* __restrict__ B0, float* __restrict__ aggr, int M) {
    constexpr int KT = NSLOT * 256;
    __shared__ __align__(16) char smem[(64 + 256) * LDSP];   // 46080 B -> 3 blocks/CU
    const int m0 = blockIdx.x * 64;
    const int tid = threadIdx.x;
    const int lane = tid & 63;
    const int wid = tid >> 6;
    const int wn = wid * 64;
    const int srow = tid >> 3;   // 0..31
    const int sc   = tid & 7;

    f32x4 acc[4][4];
#pragma unroll
    for (int i = 0; i < 4; ++i)
#pragma unroll
        for (int j = 0; j < 4; ++j)
            acc[i][j] = f32x4{0.f, 0.f, 0.f, 0.f};

    uint4 ra[2], rb[8];
    auto load_tile = [&](int k0) {
        const int slot = k0 >> 8;
        const int kin = k0 & 255;
#pragma unroll
        for (int i = 0; i < 2; ++i) {
            int m = m0 + i * 32 + srow; m = (m < M) ? m : (M - 1);
            ra[i] = *(const uint4*)(A0 + slot * ablk + (size_t)m * 256 + kin + sc * 8);
        }
#pragma unroll
        for (int j = 0; j < 8; ++j)
            rb[j] = *(const uint4*)(B0 + (size_t)slot * 65536
                                    + (size_t)(j * 32 + srow) * 256 + kin + sc * 8);
    };

    load_tile(0);
    for (int k0 = 0; k0 < KT; k0 += 64) {
        __syncthreads();
#pragma unroll
        for (int i = 0; i < 2; ++i)
            *(uint4*)(smem + (i * 32 + srow) * LDSP + sc * 16) = ra[i];
#pragma unroll
        for (int j = 0; j < 8; ++j)
            *(uint4*)(smem + BOFF + (j * 32 + srow) * LDSP + sc * 16) = rb[j];
        __syncthreads();
        if (k0 + 64 < KT) load_tile(k0 + 64);
#pragma unroll
        for (int ks = 0; ks < 2; ++ks) {
            const int koff = ks * 64 + (lane >> 4) * 16;
            bf16x8 af[4], bf[4];
#pragma unroll
            for (int mi = 0; mi < 4; ++mi)
                af[mi] = *(const bf16x8*)(smem + (mi * 16 + (lane & 15)) * LDSP + koff);
#pragma unroll
            for (int ni = 0; ni < 4; ++ni)
                bf[ni] = *(const bf16x8*)(smem + BOFF + (wn + ni * 16 + (lane & 15)) * LDSP + koff);
#pragma unroll
            for (int mi = 0; mi < 4; ++mi)
#pragma unroll
                for (int ni = 0; ni < 4; ++ni)
                    acc[mi][ni] = __builtin_amdgcn_mfma_f32_16x16x32_bf16(
                        af[mi], bf[ni], acc[mi][ni], 0, 0, 0);
        }
    }

    const int colb = wn + (lane & 15);
#pragma unroll
    for (int mi = 0; mi < 4; ++mi) {
        int mbase = m0 + mi * 16 + ((lane >> 4) << 2);
#pragma unroll
        for (int r = 0; r < 4; ++r) {
            int m = mbase + r;
            if (m < M) {
#pragma unroll
                for (int ni = 0; ni < 4; ++ni) {
                    size_t idx = (size_t)m * 256 + colb + ni * 16;
                    if constexpr (INIT) aggr[idx] = acc[mi][ni][r];
                    else                aggr[idx] += acc[mi][ni][r];
                }
            }
        }
    }
}

// ---------------- h = LN(relu(agg)) -> bf16 ----------------
__global__ __launch_bounds__(256)
void relu_ln_kernel(const float* __restrict__ agg, const float* __restrict__ g,
                    const float* __restrict__ b, u16* __restrict__ hb, int n) {
    int wid = threadIdx.x >> 6, lane = threadIdx.x & 63;
    int row = blockIdx.x * 4 + wid;
    if (row >= n) return;
    float4 v = *(const float4*)(agg + row * D + lane * 4);
    v.x = fmaxf(v.x, 0.f); v.y = fmaxf(v.y, 0.f);
    v.z = fmaxf(v.z, 0.f); v.w = fmaxf(v.w, 0.f);
    float s  = v.x + v.y + v.z + v.w;
    float s2 = v.x * v.x + v.y * v.y + v.z * v.z + v.w * v.w;
#pragma unroll
    for (int off = 1; off < 64; off <<= 1) {
        s  += __shfl_xor(s, off);
        s2 += __shfl_xor(s2, off);
    }
    float mu = s * 0.00390625f;
    float var = s2 * 0.00390625f - mu * mu;
    float rs = rsqrtf(var + 1e-5f);
    float4 gg = *(const float4*)(g + lane * 4);
    float4 bb = *(const float4*)(b + lane * 4);
    ushort4 o;
    o.x = f2b((v.x - mu) * rs * gg.x + bb.x);
    o.y = f2b((v.y - mu) * rs * gg.y + bb.y);
    o.z = f2b((v.z - mu) * rs * gg.z + bb.z);
    o.w = f2b((v.w - mu) * rs * gg.w + bb.w);
    *(ushort4*)(hb + row * D + lane * 4) = o;
}

// ---------------- head layers ----------------
__global__ __launch_bounds__(256)
void head_layer(const u16* __restrict__ hb, const int* __restrict__ tgt,
                const float* __restrict__ inf,
                const float* __restrict__ W, const float* __restrict__ bias,
                const float* __restrict__ g, const float* __restrict__ beta,
                float* __restrict__ out, int gather) {
    __shared__ float xr[256];
    __shared__ float sm1[4], sm2[4];
    int t = blockIdx.x, tid = threadIdx.x;
    if (gather) { int node = tgt[t]; xr[tid] = b2f(hb[node * D + tid]); }
    else        { xr[tid] = inf[t * D + tid]; }
    __syncthreads();
    float a = bias[tid];
#pragma unroll 8
    for (int k = 0; k < 256; ++k) a = fmaf(xr[k], W[k * 256 + tid], a);
    float s = a, s2 = a * a;
#pragma unroll
    for (int off = 1; off < 64; off <<= 1) {
        s  += __shfl_xor(s, off);
        s2 += __shfl_xor(s2, off);
    }
    int wid = tid >> 6, lane = tid & 63;
    if (lane == 0) { sm1[wid] = s; sm2[wid] = s2; }
    __syncthreads();
    s  = sm1[0] + sm1[1] + sm1[2] + sm1[3];
    s2 = sm2[0] + sm2[1] + sm2[2] + sm2[3];
    float mu = s * 0.00390625f;
    float var = s2 * 0.00390625f - mu * mu;
    float rs = rsqrtf(var + 1e-5f);
    float y = (a - mu) * rs * g[tid] + beta[tid];
    out[t * 256 + tid] = fmaxf(y, 0.f);
}

__global__ __launch_bounds__(256)
void head_out(const float* __restrict__ in, const float* __restrict__ ow,
              const float* __restrict__ ob, float* __restrict__ out, int T) {
    int wid = threadIdx.x >> 6, lane = threadIdx.x & 63;
    int t = blockIdx.x * 4 + wid;
    if (t >= T) return;
    float4 v = *(const float4*)(in + t * D + lane * 4);
    float4 w = *(const float4*)(ow + lane * 4);
    float s = v.x * w.x + v.y * w.y + v.z * w.z + v.w * w.w;
#pragma unroll
    for (int off = 1; off < 64; off <<= 1) s += __shfl_xor(s, off);
    if (lane == 0) out[t] = s + ob[0];
}

extern "C" void kernel_launch(void* const* d_in, const int* in_sizes, int n_in,
                              void* d_out, int out_size, void* d_ws, size_t ws_size,
                              hipStream_t stream) {
    (void)in_sizes; (void)n_in; (void)out_size; (void)ws_size;
    const int*   x      = (const int*)d_in[0];
    const int*   e2     = (const int*)d_in[2];
    const int*   e3     = (const int*)d_in[3];
    const int*   tgt    = (const int*)d_in[4];
    const float* emb    = (const float*)d_in[5];
    const float* W_root = (const float*)d_in[6];
    const float* W_e2   = (const float*)d_in[7];
    const float* W_e3   = (const float*)d_in[8];
    const float* ln_g   = (const float*)d_in[9];
    const float* ln_b   = (const float*)d_in[10];
    const float* reg_W  = (const float*)d_in[11];
    const float* reg_b  = (const float*)d_in[12];
    const float* rln_g  = (const float*)d_in[13];
    const float* rln_b  = (const float*)d_in[14];
    const float* out_W  = (const float*)d_in[15];
    const float* out_b  = (const float*)d_in[16];
    float* out = (float*)d_out;

    // workspace layout — top 218,941,184 B (round 8 proved >= 221,036,032 is safe)
    char* ws = (char*)d_ws;
    float* agg    = (float*)(ws);                     // 102,400,000 B
    int*   counts = (int*)  (ws);                     // aliases agg (dead until layer 0)
    u16*   hb     = (u16*)  (ws + 102400000);         //  51,200,000
    u16*   Wr     = (u16*)  (ws + 153600000);         //     524,288
    u16*   W2c    = (u16*)  (ws + 154124288);         //   2,097,152
    u16*   W3c    = (u16*)  (ws + 156221440);         //   4,718,592
    int*   sorted2= (int*)  (ws + 160940032);         //   2,400,000
    int*   sorted3= (int*)  (ws + 163340032);         //   2,400,000
    int*   rp     = (int*)  (ws + 165740032);         //   2,000,020 (5 x 100001)
    u16*   G      = (u16*)  (ws + 167740160);         //  51,201,024 max (3 x 33334 x 256)
    float* t0     = (float*)(ws + 167740160);         // alias G (dead after layers)
    float* t1     = (float*)(ws + 169788160);

    embed_kernel<<<N_NODES / 4, 256, 0, stream>>>(x, emb, hb, N_NODES);
    convert_wt<<<(NLAYER * 256 * 256 + 255) / 256, 256, 0, stream>>>(W_root, Wr, NLAYER * 256 * 256, 256, 256);
    convert_cat<<<(NLAYER * 4 * 65536 + 255) / 256, 256, 0, stream>>>(W_e2, W2c, 2, NLAYER * 4 * 65536);
    convert_cat<<<(NLAYER * 9 * 65536 + 255) / 256, 256, 0, stream>>>(W_e3, W3c, 3, NLAYER * 9 * 65536);

    zero_counts<<<(NSEG * NBINS + 255) / 256, 256, 0, stream>>>(counts);
    hist_kernel<<<(TOTENT + 255) / 256, 256, 0, stream>>>(e2, e3, counts);
    scan_kernel<<<NSEG, 1024, 0, stream>>>(counts);
    copy_rowptr<<<(NSEG * RPW + 255) / 256, 256, 0, stream>>>(counts, rp);
    scatter_kernel<<<(TOTENT + 255) / 256, 256, 0, stream>>>(e2, e3, counts, sorted2, sorted3);

    // M-chunking: e2 halves, e3 thirds (G buffer cap)
    const int h2n[2] = {50000, 50000};          const int h2o[2] = {0, 50000};
    const int h3n[3] = {33334, 33334, 33332};   const int h3o[3] = {0, 33334, 66668};

    for (int l = 0; l < NLAYER; ++l) {
        // root: agg = h @ W_root[l]
        gemm_acc<1, true><<<(N_NODES + 63) / 64, 256, 0, stream>>>(
            hb, 0, Wr + (size_t)l * 65536, agg, N_NODES);
        // e2: per dst-slot s, per M-half: G_t = CSR-aggregate(h); agg += [G_0 G_1] @ W2[:,s]
        for (int s = 0; s < 2; ++s)
            for (int hh = 0; hh < 2; ++hh) {
                int n0 = h2o[hh], nr = h2n[hh];
                gather_agg<2><<<(nr + 7) / 8, 256, 0, stream>>>(
                    hb, e2, sorted2 + (size_t)s * E2N, rp + s * RPW, G, n0, nr, E2N, nr * 256);
                gemm_acc<2, false><<<(nr + 63) / 64, 256, 0, stream>>>(
                    G, (size_t)nr * 256, W2c + (size_t)((l * 2 + s) * 2) * 65536,
                    agg + (size_t)n0 * 256, nr);
            }
        // e3: per dst-slot s, per M-third: agg += [G_0 G_1 G_2] @ W3[:,s]
        for (int s = 0; s < 3; ++s)
            for (int hh = 0; hh < 3; ++hh) {
                int n0 = h3o[hh], nr = h3n[hh];
                gather_agg<3><<<(nr + 7) / 8, 256, 0, stream>>>(
                    hb, e3, sorted3 + (size_t)s * E3N, rp + (2 + s) * RPW, G, n0, nr, E3N, nr * 256);
                gemm_acc<3, false><<<(nr + 63) / 64, 256, 0, stream>>>(
                    G, (size_t)nr * 256, W3c + (size_t)((l * 3 + s) * 3) * 65536,
                    agg + (size_t)n0 * 256, nr);
            }
        relu_ln_kernel<<<N_NODES / 4, 256, 0, stream>>>(agg, ln_g + l * D, ln_b + l * D, hb, N_NODES);
    }

    head_layer<<<TGT, 256, 0, stream>>>(hb, tgt, nullptr, reg_W, reg_b, rln_g, rln_b, t0, 1);
    head_layer<<<TGT, 256, 0, stream>>>(nullptr, nullptr, t0, reg_W + 65536, reg_b + 256, rln_g + 256, rln_b + 256, t1, 0);
    head_out<<<(TGT + 3) / 4, 256, 0, stream>>>(t1, out_W, out_b, out, TGT);
}

// Round 10
// 5372.793 us; speedup vs baseline: 1.8855x; 1.8855x over previous
//
#include <hip/hip_runtime.h>

typedef unsigned short u16;
typedef __bf16 bf16x8 __attribute__((ext_vector_type(8)));
typedef float f32x4 __attribute__((ext_vector_type(4)));

#define N_NODES 100000
#define D 256
#define NLAYER 4
#define E2N 300000
#define E3N 200000
#define TGT 2000

__device__ __forceinline__ u16 f2b(float f) {
    union { float f; unsigned u; } v; v.f = f;
    unsigned r = v.u + 0x7FFFu + ((v.u >> 16) & 1u);
    return (u16)(r >> 16);
}
__device__ __forceinline__ float b2f(u16 u) {
    union { unsigned u; float f; } v; v.u = ((unsigned)u) << 16; return v.f;
}

// async global->LDS, 16B per lane (lds dest = uniform base + lane*16)
__device__ __forceinline__ void gload16(const void* g, void* l) {
    __builtin_amdgcn_global_load_lds(
        (const __attribute__((address_space(1))) void*)g,
        (__attribute__((address_space(3))) void*)l, 16, 0, 0);
}

// ---------------- embedding gather ----------------
__global__ __launch_bounds__(256)
void embed_kernel(const int* __restrict__ x, const float* __restrict__ emb,
                  u16* __restrict__ hb, int n) {
    int wid = threadIdx.x >> 6, lane = threadIdx.x & 63;
    int row = blockIdx.x * 4 + wid;
    if (row >= n) return;
    int v = x[row];
    float4 f = *(const float4*)(emb + v * D + lane * 4);
    ushort4 o; o.x = f2b(f.x); o.y = f2b(f.y); o.z = f2b(f.z); o.w = f2b(f.w);
    *(ushort4*)(hb + row * D + lane * 4) = o;
}

// ---------------- W_root (L,K,N) f32 -> Wr (L,N,K) bf16 ----------------
__global__ __launch_bounds__(256)
void convert_wt(const float* __restrict__ W, u16* __restrict__ Wt,
                int total, int K, int N) {
    int idx = blockIdx.x * 256 + threadIdx.x;
    if (idx >= total) return;
    int kk = idx % K;
    int rem = idx / K;
    int nn = rem % N;
    int l  = rem / N;
    Wt[idx] = f2b(W[(l * K + kk) * N + nn]);
}

// ---------------- W_eA (L, A*256, A*256) -> Wcat[((l*A+s)*A+t)][c][k] ----------------
__global__ __launch_bounds__(256)
void convert_cat(const float* __restrict__ W, u16* __restrict__ Wt,
                 int A, int total) {
    int idx = blockIdx.x * 256 + threadIdx.x;
    if (idx >= total) return;
    int k = idx & 255;
    int c = (idx >> 8) & 255;
    int r = idx >> 16;           // (l*A + s)*A + t
    int t = r % A; int ls = r / A; int s = ls % A; int l = ls / A;
    int AD = A * 256;
    Wt[idx] = f2b(W[(size_t)(l * AD + t * 256 + k) * AD + s * 256 + c]);
}

// ---------------- counting sort: CSR (rowptr + edge-id col array) per (type,slot) ------
#define NBINS 100000
#define NSEG 5
#define TOTENT 1200000
#define RPW (NBINS + 1)

__global__ __launch_bounds__(256)
void zero_counts(int* __restrict__ counts) {
    int i = blockIdx.x * 256 + threadIdx.x;
    if (i < NSEG * NBINS) counts[i] = 0;
}

__device__ __forceinline__ void decode_entry(int i, const int* e2, const int* e3,
                                             int& seg, int& key, int& e, int& is2) {
    if (i < 2 * E2N) {
        int s = i / E2N; e = i - s * E2N;
        seg = s; key = e2[s * E2N + e]; is2 = 1;
    } else {
        int j = i - 2 * E2N; int s = j / E3N; e = j - s * E3N;
        seg = 2 + s; key = e3[s * E3N + e]; is2 = 0;
    }
}

__global__ __launch_bounds__(256)
void hist_kernel(const int* __restrict__ e2, const int* __restrict__ e3,
                 int* __restrict__ counts) {
    int i = blockIdx.x * 256 + threadIdx.x;
    if (i >= TOTENT) return;
    int seg, key, e, is2;
    decode_entry(i, e2, e3, seg, key, e, is2);
    atomicAdd(counts + seg * NBINS + key, 1);
}

__global__ __launch_bounds__(1024)
void scan_kernel(int* __restrict__ counts) {
    __shared__ int ps[1024];
    int* seg = counts + blockIdx.x * NBINS;
    int t = threadIdx.x;
    const int C = (NBINS + 1023) / 1024;
    int b = t * C, en = b + C; if (en > NBINS) en = NBINS; if (b > NBINS) b = NBINS;
    int s = 0;
    for (int i = b; i < en; ++i) s += seg[i];
    ps[t] = s; __syncthreads();
    for (int off = 1; off < 1024; off <<= 1) {
        int v = ps[t];
        if (t >= off) v += ps[t - off];
        __syncthreads();
        ps[t] = v; __syncthreads();
    }
    int run = (t == 0) ? 0 : ps[t - 1];
    for (int i = b; i < en; ++i) { int c = seg[i]; seg[i] = run; run += c; }
}

__global__ __launch_bounds__(256)
void copy_rowptr(const int* __restrict__ counts, int* __restrict__ rp) {
    int i = blockIdx.x * 256 + threadIdx.x;
    if (i >= NSEG * RPW) return;
    int seg = i / RPW, k = i - seg * RPW;
    rp[i] = (k < NBINS) ? counts[seg * NBINS + k] : (seg < 2 ? E2N : E3N);
}

__global__ __launch_bounds__(256)
void scatter_kernel(const int* __restrict__ e2, const int* __restrict__ e3,
                    int* __restrict__ counts, int* __restrict__ sorted2,
                    int* __restrict__ sorted3) {
    int i = blockIdx.x * 256 + threadIdx.x;
    if (i >= TOTENT) return;
    int seg, key, e, is2;
    decode_entry(i, e2, e3, seg, key, e, is2);
    int pos = atomicAdd(counts + seg * NBINS + key, 1);
    if (is2) sorted2[seg * E2N + pos] = e;
    else     sorted3[(seg - 2) * E3N + pos] = e;
}

// ---------------- CSR gather for one (seg,t): G[n,:] = sum_{e: dst=n} h[src_t(e),:] ----
// One wave per dst node; lane covers 4 cols (8B). No intra-wave divergence.
__global__ __launch_bounds__(256)
void gather1(const u16* __restrict__ hb, const int* __restrict__ src_ids,
             const int* __restrict__ csr, const int* __restrict__ rp,
             u16* __restrict__ G) {
    int node = (blockIdx.x * 256 + threadIdx.x) >> 6;
    int lane = threadIdx.x & 63;
    if (node >= N_NODES) return;
    int e0 = rp[node], e1 = rp[node + 1];
    float4 acc = {0.f, 0.f, 0.f, 0.f};
    int e = e0;
    for (; e + 1 < e1; e += 2) {
        int s0 = src_ids[csr[e]];
        int s1 = src_ids[csr[e + 1]];
        ushort4 a = *(const ushort4*)(hb + (size_t)s0 * 256 + lane * 4);
        ushort4 b = *(const ushort4*)(hb + (size_t)s1 * 256 + lane * 4);
        acc.x += b2f(a.x) + b2f(b.x);
        acc.y += b2f(a.y) + b2f(b.y);
        acc.z += b2f(a.z) + b2f(b.z);
        acc.w += b2f(a.w) + b2f(b.w);
    }
    if (e < e1) {
        int s0 = src_ids[csr[e]];
        ushort4 a = *(const ushort4*)(hb + (size_t)s0 * 256 + lane * 4);
        acc.x += b2f(a.x); acc.y += b2f(a.y);
        acc.z += b2f(a.z); acc.w += b2f(a.w);
    }
    ushort4 o; o.x = f2b(acc.x); o.y = f2b(acc.y); o.z = f2b(acc.z); o.w = f2b(acc.w);
    *(ushort4*)(G + (size_t)node * 256 + lane * 4) = o;
}

// ---------------- m97-style GEMM: agg[m, n0:n0+128] (+)= A[m,:256] @ B[n,:256]^T -------
// A: dense [M x 256] bf16. B: [256 x 256] bf16, row n = output col, K-contiguous.
// 128x128 tile, BK=64, 4 waves (2x2 quadrants), global_load_lds(16) staging,
// single-buffer 2-barrier K-loop (m97 structure).
template<bool INIT>
__global__ __launch_bounds__(256)
void gemm128(const u16* __restrict__ A, const u16* __restrict__ B,
             float* __restrict__ aggr, int M) {
    __shared__ __align__(16) u16 sA[128 * 64];
    __shared__ __align__(16) u16 sB[128 * 64];
    const int bid = blockIdx.x;
    const int mt = bid >> 1;
    const int nt = bid & 1;
    const int m0 = mt * 128;
    const int n0 = nt * 128;
    const int tid = threadIdx.x;
    const int lane = tid & 63;
    const int wid = tid >> 6;
    const int wm = (wid >> 1) * 64;
    const int wn = (wid & 1) * 64;
    const int lrow8 = lane >> 3;     // 0..7 row within 8-row group
    const int lcol  = (lane & 7) * 8; // elem offset within 64-elem row slice

    f32x4 acc[4][4];
#pragma unroll
    for (int i = 0; i < 4; ++i)
#pragma unroll
        for (int j = 0; j < 4; ++j)
            acc[i][j] = f32x4{0.f, 0.f, 0.f, 0.f};

    for (int k0 = 0; k0 < 256; k0 += 64) {
        __syncthreads();   // all waves done reading LDS from previous step
#pragma unroll
        for (int i = 0; i < 4; ++i) {
            int row = wid * 32 + i * 8;          // base row of this 8-row group
            int ar = m0 + row + lrow8; ar = (ar < M) ? ar : (M - 1);
            gload16(A + (size_t)ar * 256 + k0 + lcol, sA + row * 64);
            gload16(B + (size_t)(n0 + row + lrow8) * 256 + k0 + lcol, sB + row * 64);
        }
        __syncthreads();   // drains vmcnt(0): staged data visible
#pragma unroll
        for (int ks = 0; ks < 2; ++ks) {
            const int koff = ks * 32 + (lane >> 4) * 8;
            bf16x8 af[4], bf[4];
#pragma unroll
            for (int mi = 0; mi < 4; ++mi)
                af[mi] = *(const bf16x8*)(sA + (wm + mi * 16 + (lane & 15)) * 64 + koff);
#pragma unroll
            for (int ni = 0; ni < 4; ++ni)
                bf[ni] = *(const bf16x8*)(sB + (wn + ni * 16 + (lane & 15)) * 64 + koff);
#pragma unroll
            for (int mi = 0; mi < 4; ++mi)
#pragma unroll
                for (int ni = 0; ni < 4; ++ni)
                    acc[mi][ni] = __builtin_amdgcn_mfma_f32_16x16x32_bf16(
                        af[mi], bf[ni], acc[mi][ni], 0, 0, 0);
        }
    }

    const int colb = n0 + wn + (lane & 15);
#pragma unroll
    for (int mi = 0; mi < 4; ++mi) {
        int mbase = m0 + wm + mi * 16 + ((lane >> 4) << 2);
#pragma unroll
        for (int r = 0; r < 4; ++r) {
            int m = mbase + r;
            if (m < M) {
#pragma unroll
                for (int ni = 0; ni < 4; ++ni) {
                    size_t idx = (size_t)m * 256 + colb + ni * 16;
                    if constexpr (INIT) aggr[idx] = acc[mi][ni][r];
                    else                aggr[idx] += acc[mi][ni][r];
                }
            }
        }
    }
}

// ---------------- h = LN(relu(agg)) -> bf16 (in place over hb) ----------------
__global__ __launch_bounds__(256)
void relu_ln_kernel(const float* __restrict__ agg, const float* __restrict__ g,
                    const float* __restrict__ b, u16* __restrict__ hb, int n) {
    int wid = threadIdx.x >> 6, lane = threadIdx.x & 63;
    int row = blockIdx.x * 4 + wid;
    if (row >= n) return;
    float4 v = *(const float4*)(agg + row * D + lane * 4);
    v.x = fmaxf(v.x, 0.f); v.y = fmaxf(v.y, 0.f);
    v.z = fmaxf(v.z, 0.f); v.w = fmaxf(v.w, 0.f);
    float s  = v.x + v.y + v.z + v.w;
    float s2 = v.x * v.x + v.y * v.y + v.z * v.z + v.w * v.w;
#pragma unroll
    for (int off = 1; off < 64; off <<= 1) {
        s  += __shfl_xor(s, off);
        s2 += __shfl_xor(s2, off);
    }
    float mu = s * 0.00390625f;
    float var = s2 * 0.00390625f - mu * mu;
    float rs = rsqrtf(var + 1e-5f);
    float4 gg = *(const float4*)(g + lane * 4);
    float4 bb = *(const float4*)(b + lane * 4);
    ushort4 o;
    o.x = f2b((v.x - mu) * rs * gg.x + bb.x);
    o.y = f2b((v.y - mu) * rs * gg.y + bb.y);
    o.z = f2b((v.z - mu) * rs * gg.z + bb.z);
    o.w = f2b((v.w - mu) * rs * gg.w + bb.w);
    *(ushort4*)(hb + row * D + lane * 4) = o;
}

// ---------------- head layers ----------------
__global__ __launch_bounds__(256)
void head_layer(const u16* __restrict__ hb, const int* __restrict__ tgt,
                const float* __restrict__ inf,
                const float* __restrict__ W, const float* __restrict__ bias,
                const float* __restrict__ g, const float* __restrict__ beta,
                float* __restrict__ out, int gather) {
    __shared__ float xr[256];
    __shared__ float sm1[4], sm2[4];
    int t = blockIdx.x, tid = threadIdx.x;
    if (gather) { int node = tgt[t]; xr[tid] = b2f(hb[node * D + tid]); }
    else        { xr[tid] = inf[t * D + tid]; }
    __syncthreads();
    float a = bias[tid];
#pragma unroll 8
    for (int k = 0; k < 256; ++k) a = fmaf(xr[k], W[k * 256 + tid], a);
    float s = a, s2 = a * a;
#pragma unroll
    for (int off = 1; off < 64; off <<= 1) {
        s  += __shfl_xor(s, off);
        s2 += __shfl_xor(s2, off);
    }
    int wid = tid >> 6, lane = tid & 63;
    if (lane == 0) { sm1[wid] = s; sm2[wid] = s2; }
    __syncthreads();
    s  = sm1[0] + sm1[1] + sm1[2] + sm1[3];
    s2 = sm2[0] + sm2[1] + sm2[2] + sm2[3];
    float mu = s * 0.00390625f;
    float var = s2 * 0.00390625f - mu * mu;
    float rs = rsqrtf(var + 1e-5f);
    float y = (a - mu) * rs * g[tid] + beta[tid];
    out[t * 256 + tid] = fmaxf(y, 0.f);
}

__global__ __launch_bounds__(256)
void head_out(const float* __restrict__ in, const float* __restrict__ ow,
              const float* __restrict__ ob, float* __restrict__ out, int T) {
    int wid = threadIdx.x >> 6, lane = threadIdx.x & 63;
    int t = blockIdx.x * 4 + wid;
    if (t >= T) return;
    float4 v = *(const float4*)(in + t * D + lane * 4);
    float4 w = *(const float4*)(ow + lane * 4);
    float s = v.x * w.x + v.y * w.y + v.z * w.z + v.w * w.w;
#pragma unroll
    for (int off = 1; off < 64; off <<= 1) s += __shfl_xor(s, off);
    if (lane == 0) out[t] = s + ob[0];
}

extern "C" void kernel_launch(void* const* d_in, const int* in_sizes, int n_in,
                              void* d_out, int out_size, void* d_ws, size_t ws_size,
                              hipStream_t stream) {
    (void)in_sizes; (void)n_in; (void)out_size; (void)ws_size;
    const int*   x      = (const int*)d_in[0];
    const int*   e2     = (const int*)d_in[2];
    const int*   e3     = (const int*)d_in[3];
    const int*   tgt    = (const int*)d_in[4];
    const float* emb    = (const float*)d_in[5];
    const float* W_root = (const float*)d_in[6];
    const float* W_e2   = (const float*)d_in[7];
    const float* W_e3   = (const float*)d_in[8];
    const float* ln_g   = (const float*)d_in[9];
    const float* ln_b   = (const float*)d_in[10];
    const float* reg_W  = (const float*)d_in[11];
    const float* reg_b  = (const float*)d_in[12];
    const float* rln_g  = (const float*)d_in[13];
    const float* rln_b  = (const float*)d_in[14];
    const float* out_W  = (const float*)d_in[15];
    const float* out_b  = (const float*)d_in[16];
    float* out = (float*)d_out;

    // workspace layout — top 218,940,160 B (within the proven 221 MB envelope)
    char* ws = (char*)d_ws;
    float* agg    = (float*)(ws);                     // 102,400,000 B
    int*   counts = (int*)  (ws);                     // aliases agg (dead until layer 0)
    u16*   hb     = (u16*)  (ws + 102400000);         //  51,200,000
    u16*   Wr     = (u16*)  (ws + 153600000);         //     524,288
    u16*   W2c    = (u16*)  (ws + 154124288);         //   2,097,152
    u16*   W3c    = (u16*)  (ws + 156221440);         //   4,718,592
    int*   sorted2= (int*)  (ws + 160940032);         //   2,400,000
    int*   sorted3= (int*)  (ws + 163340032);         //   2,400,000
    int*   rp     = (int*)  (ws + 165740032);         //   2,000,020 (5 x 100001)
    u16*   G      = (u16*)  (ws + 167740160);         //  51,200,000 (100k x 256 bf16)
    float* t0     = (float*)(ws + 167740160);         // alias G (dead after layers)
    float* t1     = (float*)(ws + 169788160);

    embed_kernel<<<N_NODES / 4, 256, 0, stream>>>(x, emb, hb, N_NODES);
    convert_wt<<<(NLAYER * 256 * 256 + 255) / 256, 256, 0, stream>>>(W_root, Wr, NLAYER * 256 * 256, 256, 256);
    convert_cat<<<(NLAYER * 4 * 65536 + 255) / 256, 256, 0, stream>>>(W_e2, W2c, 2, NLAYER * 4 * 65536);
    convert_cat<<<(NLAYER * 9 * 65536 + 255) / 256, 256, 0, stream>>>(W_e3, W3c, 3, NLAYER * 9 * 65536);

    zero_counts<<<(NSEG * NBINS + 255) / 256, 256, 0, stream>>>(counts);
    hist_kernel<<<(TOTENT + 255) / 256, 256, 0, stream>>>(e2, e3, counts);
    scan_kernel<<<NSEG, 1024, 0, stream>>>(counts);
    copy_rowptr<<<(NSEG * RPW + 255) / 256, 256, 0, stream>>>(counts, rp);
    scatter_kernel<<<(TOTENT + 255) / 256, 256, 0, stream>>>(e2, e3, counts, sorted2, sorted3);

    const int ggrid = (N_NODES * 64 + 255) / 256;       // 25000 (1 wave / node)
    const int mgrid = ((N_NODES + 127) / 128) * 2;      // 782 m-tiles x 2 n-tiles = 1564

    for (int l = 0; l < NLAYER; ++l) {
        // root: agg = h @ W_root[l]
        gemm128<true><<<mgrid, 256, 0, stream>>>(hb, Wr + (size_t)l * 65536, agg, N_NODES);
        // e2: per (dst-slot s, src-slot t): G = CSR-agg(h, src_t); agg += G @ W2[t,s]
        for (int s = 0; s < 2; ++s)
            for (int t = 0; t < 2; ++t) {
                gather1<<<ggrid, 256, 0, stream>>>(
                    hb, e2 + (size_t)t * E2N, sorted2 + (size_t)s * E2N, rp + s * RPW, G);
                gemm128<false><<<mgrid, 256, 0, stream>>>(
                    G, W2c + (size_t)((l * 2 + s) * 2 + t) * 65536, agg, N_NODES);
            }
        // e3: 3x3 slot pairs
        for (int s = 0; s < 3; ++s)
            for (int t = 0; t < 3; ++t) {
                gather1<<<ggrid, 256, 0, stream>>>(
                    hb, e3 + (size_t)t * E3N, sorted3 + (size_t)s * E3N, rp + (2 + s) * RPW, G);
                gemm128<false><<<mgrid, 256, 0, stream>>>(
                    G, W3c + (size_t)((l * 3 + s) * 3 + t) * 65536, agg, N_NODES);
            }
        relu_ln_kernel<<<N_NODES / 4, 256, 0, stream>>>(agg, ln_g + l * D, ln_b + l * D, hb, N_NODES);
    }

    head_layer<<<TGT, 256, 0, stream>>>(hb, tgt, nullptr, reg_W, reg_b, rln_g, rln_b, t0, 1);
    head_layer<<<TGT, 256, 0, stream>>>(nullptr, nullptr, t0, reg_W + 65536, reg_b + 256, rln_g + 256, rln_b + 256, t1, 0);
    head_out<<<(TGT + 3) / 4, 256, 0, stream>>>(t1, out_W, out_b, out, TGT);
}